// Round 9
// baseline (145.685 us; speedup 1.0000x reference)
//
#include <hip/hip_runtime.h>
#include <hip/hip_bf16.h>
#include <math.h>

#define B_TOT 8192
#define OBS   4096
#define NG    4
#define GSZ   1024
#define LATD  64
#define HDIM  128

typedef __attribute__((ext_vector_type(8))) short   short8_t;
typedef __attribute__((ext_vector_type(8))) unsigned short ushort8_t;
typedef __attribute__((ext_vector_type(4))) float   float4_t;

__constant__ int kMask[15] = {1,2,4,8, 3,5,9,6,10,12, 7,11,13,14, 15};

static __device__ __forceinline__ unsigned short f2b(float x) {
  __hip_bfloat16 b = __float2bfloat16(x);
  return *reinterpret_cast<unsigned short*>(&b);
}
static __device__ __forceinline__ unsigned int pack2(float lo, float hi) {
  return (unsigned int)f2b(lo) | ((unsigned int)f2b(hi) << 16);
}

// ------------- weight prep: bf16 + fragment-panel layouts ------------------
// All panels: per (ks,ni) a 512-short slab [l15][oct][j] -> wave B-load = 64
// lanes x 16B contiguous. k = ks*32 + oct*8 + j.
// Strides IN SHORTS: W1p: ni 512, ks 1024, (g,w) 32768
//                    W2p: ni 512, ks 4096, g 16384
//                    W3p: ni 512, ks 2048, g 4096
//                    W4p: ni 512, ks 1024, oh 2048, ob 4096, g 65536
#define N1 524288
#define N2 65536
#define N3 16384
#define N4 262144
__global__ __launch_bounds__(256) void k_prep(const float* __restrict__ w1,
                                              const float* __restrict__ w2,
                                              const float* __restrict__ w3,
                                              const float* __restrict__ w4,
                                              unsigned short* __restrict__ W1p,
                                              unsigned short* __restrict__ W2p,
                                              unsigned short* __restrict__ W3p,
                                              unsigned short* __restrict__ W4p) {
  const int i = blockIdx.x * 256 + threadIdx.x;
  if (i < N1) {
    // bits: j(3) oct(2) l15(4) ni(1) ks(5) w(2) g(2)
    const int j = i & 7, oct = (i >> 3) & 3, l15 = (i >> 5) & 15;
    const int ni = (i >> 9) & 1, ks = (i >> 10) & 31;
    const int w = (i >> 15) & 3, g = (i >> 17) & 3;
    const int k = ks * 32 + oct * 8 + j;
    const int h = w * 32 + ni * 16 + l15;
    W1p[i] = f2b(w1[g * 131072 + k * 128 + h]);
  } else if (i < N1 + N2) {
    const int idx = i - N1;     // bits: j oct l15 ni(3) ks(2) g(2)
    const int j = idx & 7, oct = (idx >> 3) & 3, l15 = (idx >> 5) & 15;
    const int ni = (idx >> 9) & 7, ks = (idx >> 12) & 3, g = (idx >> 14) & 3;
    const int k = ks * 32 + oct * 8 + j;
    const int col = ni * 16 + l15;
    W2p[idx] = f2b(w2[g * 16384 + k * 128 + col]);
  } else if (i < N1 + N2 + N3) {
    const int idx = i - N1 - N2;  // bits: j oct l15 ni(2) ks(1) g(2)
    const int j = idx & 7, oct = (idx >> 3) & 3, l15 = (idx >> 5) & 15;
    const int ni = (idx >> 9) & 3, ks = (idx >> 11) & 1, g = (idx >> 12) & 3;
    const int k = ks * 32 + oct * 8 + j;
    const int m = ni * 16 + l15;
    W3p[idx] = f2b(w3[g * 4096 + k * 64 + m]);
  } else if (i < N1 + N2 + N3 + N4) {
    const int idx = i - N1 - N2 - N3;  // bits: j oct l15 ni(1) ks(1) oh(1) ob(4) g(2)
    const int j = idx & 7, oct = (idx >> 3) & 3, l15 = (idx >> 5) & 15;
    const int ni = (idx >> 9) & 1, ks = (idx >> 10) & 1;
    const int oh = (idx >> 11) & 1, ob = (idx >> 12) & 15, g = (idx >> 16) & 3;
    const int k = ks * 32 + oct * 8 + j;
    const int o = ob * 64 + oh * 32 + ni * 16 + l15;
    W4p[idx] = f2b(w4[g * 65536 + k * 1024 + o]);
  }
}

// ---------------- X transpose: Xt[b][g][k] = bf16(X[b][4k+g]) --------------
__global__ __launch_bounds__(512) void k_prepx(const float* __restrict__ X,
                                               unsigned short* __restrict__ Xt) {
  const int t = threadIdx.x;
  const int b = blockIdx.x * 2 + (t >> 8);
  const int c = (t & 255) * 16;               // float col 0..4080
  const float* p = X + (size_t)b * OBS + c;
  const float4_t f0 = *(const float4_t*)(p);
  const float4_t f1 = *(const float4_t*)(p + 4);
  const float4_t f2 = *(const float4_t*)(p + 8);
  const float4_t f3 = *(const float4_t*)(p + 12);
  const int k0 = c >> 2;
  unsigned short* q = Xt + (size_t)b * OBS;
#pragma unroll
  for (int g = 0; g < 4; ++g) {
    uint2 v;
    v.x = pack2(f0[g], f1[g]);
    v.y = pack2(f2[g], f3[g]);
    *(uint2*)(q + g * GSZ + k0) = v;
  }
}

// ---------------- enc1: Hbf = relu(Xg @ enc_w1 + b1) -----------------------
// grid (256 rb, 4 g) x 256 thr (4 waves). Block: 32 rows x 128 h (one g).
// Wave w: 32r x 32h (2x2 frags). Stage A once (66KB LDS), then BARRIER-FREE
// 32-kstep loop: 2 ds_read + 2 contiguous panel loads + 4 MFMA.
#define ARS 1032   // lA row stride in shorts
__global__ __launch_bounds__(256, 2) void k_enc1(const unsigned short* __restrict__ Xt,
                                                 const unsigned short* __restrict__ W1p,
                                                 const float* __restrict__ B1,
                                                 unsigned short* __restrict__ Hbf) {
  __shared__ union {
    unsigned short lA[32 * ARS];        // 66 KB
    unsigned short ob[32][136];         // epilogue repack
  } s;
  const int tid = threadIdx.x;
  const int w   = tid >> 6;
  const int l   = tid & 63;
  const int l15 = l & 15;
  const int oct = l >> 4;
  const int rb  = blockIdx.x * 32;
  const int g   = blockIdx.y;
  const int lofs = (l15 * 4 + oct) * 8;

  // stage: thread = (row 0..31, seg 0..7); 256B contiguous per thread
  {
    const int row = tid >> 3, seg = tid & 7;
    const unsigned short* src = Xt + (size_t)(rb + row) * OBS + g * GSZ + seg * 128;
    unsigned short* dst = &s.lA[row * ARS + seg * 128];
#pragma unroll
    for (int i = 0; i < 16; ++i)
      *(ushort8_t*)(dst + i * 8) = *(const ushort8_t*)(src + i * 8);
  }
  __syncthreads();

  float4_t acc[2][2];
#pragma unroll
  for (int i = 0; i < 2; ++i)
#pragma unroll
    for (int j = 0; j < 2; ++j) acc[i][j] = (float4_t){0.f, 0.f, 0.f, 0.f};

  // CORRECT short-unit strides: (g,w) panel = 32768 shorts, ks = 1024, ni = 512
  const unsigned short* bb = W1p + (size_t)(g * 4 + w) * 32768 + lofs;

  // barrier-free K loop
#pragma unroll 4
  for (int ks = 0; ks < 32; ++ks) {
    short8_t af[2], bf[2];
#pragma unroll
    for (int mi = 0; mi < 2; ++mi)
      af[mi] = *(const short8_t*)&s.lA[(mi * 16 + l15) * ARS + ks * 32 + oct * 8];
#pragma unroll
    for (int ni = 0; ni < 2; ++ni)
      bf[ni] = *(const short8_t*)(bb + ks * 1024 + ni * 512);
#pragma unroll
    for (int mi = 0; mi < 2; ++mi)
#pragma unroll
      for (int ni = 0; ni < 2; ++ni)
        acc[mi][ni] = __builtin_amdgcn_mfma_f32_16x16x32_bf16(af[mi], bf[ni], acc[mi][ni], 0, 0, 0);
  }
  __syncthreads();   // lA dead; ob overlays

  // epilogue: bias+relu -> ob -> coalesced Hbf rows
#pragma unroll
  for (int ni = 0; ni < 2; ++ni) {
    const int hcol = w * 32 + ni * 16 + l15;        // 0..127
    const float b = B1[g * 128 + hcol];
#pragma unroll
    for (int mi = 0; mi < 2; ++mi)
#pragma unroll
      for (int j = 0; j < 4; ++j)
        s.ob[mi * 16 + oct * 4 + j][hcol] = f2b(fmaxf(acc[mi][ni][j] + b, 0.0f));
  }
  __syncthreads();
  {
    const int row = tid >> 3, ch = tid & 7;
    unsigned short* dst = Hbf + (size_t)(rb + row) * 512 + g * 128 + ch * 16;
    *(ushort8_t*)(dst)     = *(const ushort8_t*)&s.ob[row][ch * 16];
    *(ushort8_t*)(dst + 8) = *(const ushort8_t*)&s.ob[row][ch * 16 + 8];
  }
}

// ------------- enc2 + PoE/sample + dec1 -> Hd ------------------------------
// 512 blocks x 256 thr (4 waves, wave = g). Block = 16 batch rows.
__global__ __launch_bounds__(256, 4) void k_enc2(const unsigned short* __restrict__ Hbf,
                                                 const unsigned short* __restrict__ W2p,
                                                 const unsigned short* __restrict__ W3p,
                                                 const float* __restrict__ B2,
                                                 const float* __restrict__ DB1,
                                                 const float* __restrict__ eps,
                                                 const int*   __restrict__ subset_idx,
                                                 unsigned short* __restrict__ Hd) {
  __shared__ union {
    unsigned short hs[16][520];
    float mls[16][516];
  } u;
  __shared__ unsigned short zb[16][72];

  const int tid = threadIdx.x;
  const int g   = tid >> 6;
  const int l   = tid & 63;
  const int l15 = l & 15;
  const int oct = l >> 4;
  const int rb  = blockIdx.x * 16;
  const int lofs = (l15 * 4 + oct) * 8;

  // stage Hbf rows
  {
    const int row = tid >> 4, p = tid & 15;
    const unsigned short* src = Hbf + (size_t)(rb + row) * 512;
#pragma unroll
    for (int i = 0; i < 4; ++i)
      *(ushort8_t*)&u.hs[row][p * 8 + i * 128] =
          *(const ushort8_t*)(src + p * 8 + i * 128);
  }
  __syncthreads();

  // enc2: wave g computes cols g*128 + ni*16 + l15, ni 0..7; K=128
  float4_t acc[8];
#pragma unroll
  for (int j = 0; j < 8; ++j) acc[j] = (float4_t){0.f, 0.f, 0.f, 0.f};
  {
    // CORRECT short-unit strides: g panel = 16384 shorts, ks = 4096, ni = 512
    const unsigned short* bb = W2p + (size_t)g * 16384 + lofs;
#pragma unroll
    for (int ks = 0; ks < 4; ++ks) {
      const short8_t af = *(const short8_t*)&u.hs[l15][g * 128 + ks * 32 + oct * 8];
#pragma unroll
      for (int ni = 0; ni < 8; ++ni) {
        const short8_t bf = *(const short8_t*)(bb + ks * 4096 + ni * 512);
        acc[ni] = __builtin_amdgcn_mfma_f32_16x16x32_bf16(af, bf, acc[ni], 0, 0, 0);
      }
    }
  }
  __syncthreads();   // hs dead; mls overlays

#pragma unroll
  for (int ni = 0; ni < 8; ++ni) {
    const int col = g * 128 + ni * 16 + l15;
    const float b = B2[col];
#pragma unroll
    for (int j = 0; j < 4; ++j)
      u.mls[oct * 4 + j][col] = acc[ni][j] + b;
  }
  __syncthreads();

  // PoE + reparameterize -> zb
#pragma unroll
  for (int qq = 0; qq < 4; ++qq) {
    const int idx = qq * 256 + tid;
    const int r   = idx >> 6;
    const int ll  = idx & 63;
    const int m   = kMask[subset_idx[rb + r]];
    float tau = 1.0f, num = 0.0f;
#pragma unroll
    for (int gg = 0; gg < 4; ++gg) {
      if (m & (1 << gg)) {
        const float lv = u.mls[r][gg * 128 + 64 + ll];
        const float mu = u.mls[r][gg * 128 + ll];
        const float t  = expf(-lv);
        tau += t;
        num = fmaf(t, mu, num);
      }
    }
    const float zv = num / tau + eps[(size_t)(rb + r) * LATD + ll] * rsqrtf(tau);
    zb[r][ll] = f2b(zv);
  }
  __syncthreads();

  // dec1: wave g -> cols g*64 + ni*16 + l15, ni 0..3; K=64
  float4_t a3[4];
#pragma unroll
  for (int j = 0; j < 4; ++j) a3[j] = (float4_t){0.f, 0.f, 0.f, 0.f};
  {
    // CORRECT short-unit strides: g panel = 4096 shorts, ks = 2048, ni = 512
    const unsigned short* bb = W3p + (size_t)g * 4096 + lofs;
#pragma unroll
    for (int ks = 0; ks < 2; ++ks) {
      const short8_t af = *(const short8_t*)&zb[l15][ks * 32 + oct * 8];
#pragma unroll
      for (int ni = 0; ni < 4; ++ni) {
        const short8_t bf = *(const short8_t*)(bb + ks * 2048 + ni * 512);
        a3[ni] = __builtin_amdgcn_mfma_f32_16x16x32_bf16(af, bf, a3[ni], 0, 0, 0);
      }
    }
  }
#pragma unroll
  for (int ni = 0; ni < 4; ++ni) {
    const int col = g * 64 + ni * 16 + l15;   // 0..255
    const float b = DB1[col];
#pragma unroll
    for (int j = 0; j < 4; ++j)
      Hd[(size_t)(rb + oct * 4 + j) * 256 + col] = f2b(fmaxf(a3[ni][j] + b, 0.0f));
  }
}

// ---------------- dec2: panel-B MFMA + coalesced epilogue ------------------
__global__ __launch_bounds__(512) void k_dec2(const unsigned short* __restrict__ Hd,
                                              const unsigned short* __restrict__ W4p,
                                              const float* __restrict__ Bb,
                                              float* __restrict__ Out) {
  __shared__ float obuf[32][264];

  const int tid = threadIdx.x;
  const int w   = tid >> 6;
  const int l   = tid & 63;
  const int g   = w >> 1;
  const int oh  = w & 1;
  const int r0  = blockIdx.x * 32;
  const int ob  = blockIdx.y * 64;
  const int l15 = l & 15;
  const int oct = l >> 4;
  const int lofs = (l15 * 4 + oct) * 8;

  float4_t acc[2][2];
#pragma unroll
  for (int i = 0; i < 2; ++i)
#pragma unroll
    for (int j = 0; j < 2; ++j) acc[i][j] = (float4_t){0.f, 0.f, 0.f, 0.f};

  const unsigned short* bb4 = W4p + ((g * 16 + blockIdx.y) * 2 + oh) * 2048 + lofs;

#pragma unroll
  for (int ks = 0; ks < 2; ++ks) {
    short8_t af[2], bf[2];
#pragma unroll
    for (int mi = 0; mi < 2; ++mi)
      af[mi] = *(const short8_t*)(Hd + (size_t)(r0 + mi * 16 + l15) * 256 +
                                  g * 64 + ks * 32 + oct * 8);
#pragma unroll
    for (int ni = 0; ni < 2; ++ni)
      bf[ni] = *(const short8_t*)(bb4 + ks * 1024 + ni * 512);
#pragma unroll
    for (int mi = 0; mi < 2; ++mi)
#pragma unroll
      for (int ni = 0; ni < 2; ++ni)
        acc[mi][ni] = __builtin_amdgcn_mfma_f32_16x16x32_bf16(af[mi], bf[ni], acc[mi][ni], 0, 0, 0);
  }

#pragma unroll
  for (int ni = 0; ni < 2; ++ni) {
    const int lo = oh * 32 + ni * 16 + l15;
    const float b = Bb[g * 1024 + ob + lo];
#pragma unroll
    for (int mi = 0; mi < 2; ++mi) {
      const int rloc = mi * 16 + oct * 4;
#pragma unroll
      for (int j = 0; j < 4; ++j)
        obuf[rloc + j][4 * lo + g] = acc[mi][ni][j] + b;
    }
  }
  __syncthreads();

#pragma unroll
  for (int i = 0; i < 4; ++i) {
    const int q = tid + i * 512;
    const int row = q >> 6, c4 = q & 63;
    const float4 v = *(const float4*)&obuf[row][c4 * 4];
    *(float4*)(Out + (size_t)(r0 + row) * OBS + 4 * ob + c4 * 4) = v;
  }
}

extern "C" void kernel_launch(void* const* d_in, const int* in_sizes, int n_in,
                              void* d_out, int out_size, void* d_ws, size_t ws_size,
                              hipStream_t stream) {
  const float* X          = (const float*)d_in[0];
  const float* eps        = (const float*)d_in[1];
  const int*   subset_idx = (const int*)  d_in[2];
  const float* enc_w1     = (const float*)d_in[3];
  const float* enc_b1     = (const float*)d_in[4];
  const float* enc_w2     = (const float*)d_in[5];
  const float* enc_b2     = (const float*)d_in[6];
  const float* dec_w1     = (const float*)d_in[7];
  const float* dec_b1     = (const float*)d_in[8];
  const float* dec_w2     = (const float*)d_in[9];
  const float* dec_b2     = (const float*)d_in[10];
  float* out = (float*)d_out;

  char* wsb = (char*)d_ws;
  unsigned short* Xt  = (unsigned short*)wsb;                                 // 64 MB
  unsigned short* Hbf = (unsigned short*)(wsb + (64u << 20));                 // 8 MB
  unsigned short* Hd  = (unsigned short*)(wsb + (72u << 20));                 // 4 MB
  unsigned short* W1p = (unsigned short*)(wsb + (76u << 20));                 // 1 MB
  unsigned short* W2p = (unsigned short*)(wsb + (77u << 20));                 // 128 KB
  unsigned short* W3p = (unsigned short*)(wsb + (77u << 20) + (128u << 10));  // 32 KB
  unsigned short* W4p = (unsigned short*)(wsb + (77u << 20) + (160u << 10));  // 512 KB

  k_prep<<<3392, 256, 0, stream>>>(enc_w1, enc_w2, dec_w1, dec_w2,
                                   W1p, W2p, W3p, W4p);
  k_prepx<<<4096, 512, 0, stream>>>(X, Xt);
  k_enc1<<<dim3(256, 4), 256, 0, stream>>>(Xt, W1p, enc_b1, Hbf);
  k_enc2<<<512, 256, 0, stream>>>(Hbf, W2p, W3p, enc_b2, dec_b1,
                                  eps, subset_idx, Hd);
  k_dec2<<<dim3(256, 16), 512, 0, stream>>>(Hd, W4p, dec_b2, out);
}

// Round 10
// 136.426 us; speedup vs baseline: 1.0679x; 1.0679x over previous
//
#include <hip/hip_runtime.h>
#include <hip/hip_bf16.h>
#include <math.h>

#define B_TOT 8192
#define OBS   4096
#define NG    4
#define GSZ   1024
#define LATD  64
#define HDIM  128

typedef __attribute__((ext_vector_type(8))) short   short8_t;
typedef __attribute__((ext_vector_type(8))) unsigned short ushort8_t;
typedef __attribute__((ext_vector_type(4))) float   float4_t;

__constant__ int kMask[15] = {1,2,4,8, 3,5,9,6,10,12, 7,11,13,14, 15};

static __device__ __forceinline__ unsigned short f2b(float x) {
  __hip_bfloat16 b = __float2bfloat16(x);
  return *reinterpret_cast<unsigned short*>(&b);
}
static __device__ __forceinline__ unsigned int pack2(float lo, float hi) {
  return (unsigned int)f2b(lo) | ((unsigned int)f2b(hi) << 16);
}
// async global->LDS, 16B per lane; dst must be wave-uniform base (HW adds lane*16)
static __device__ __forceinline__ void gl16(const void* g, void* l) {
  __builtin_amdgcn_global_load_lds(
      (const __attribute__((address_space(1))) void*)g,
      (__attribute__((address_space(3))) void*)l, 16, 0, 0);
}

// quad-padded A/h row addressing: 4 rows x 256B per 1056B issue slot
#define AQ(row) ((((row) >> 2) * 1056) + (((row) & 3) * 256))

// ------------- weight prep: bf16 + fragment-panel layouts (R9, verified) ---
#define N1 524288
#define N2 65536
#define N3 16384
#define N4 262144
__global__ __launch_bounds__(256) void k_prep(const float* __restrict__ w1,
                                              const float* __restrict__ w2,
                                              const float* __restrict__ w3,
                                              const float* __restrict__ w4,
                                              unsigned short* __restrict__ W1p,
                                              unsigned short* __restrict__ W2p,
                                              unsigned short* __restrict__ W3p,
                                              unsigned short* __restrict__ W4p) {
  const int i = blockIdx.x * 256 + threadIdx.x;
  if (i < N1) {
    const int j = i & 7, oct = (i >> 3) & 3, l15 = (i >> 5) & 15;
    const int ni = (i >> 9) & 1, ks = (i >> 10) & 31;
    const int w = (i >> 15) & 3, g = (i >> 17) & 3;
    const int k = ks * 32 + oct * 8 + j;
    const int h = w * 32 + ni * 16 + l15;
    W1p[i] = f2b(w1[g * 131072 + k * 128 + h]);
  } else if (i < N1 + N2) {
    const int idx = i - N1;
    const int j = idx & 7, oct = (idx >> 3) & 3, l15 = (idx >> 5) & 15;
    const int ni = (idx >> 9) & 7, ks = (idx >> 12) & 3, g = (idx >> 14) & 3;
    const int k = ks * 32 + oct * 8 + j;
    const int col = ni * 16 + l15;
    W2p[idx] = f2b(w2[g * 16384 + k * 128 + col]);
  } else if (i < N1 + N2 + N3) {
    const int idx = i - N1 - N2;
    const int j = idx & 7, oct = (idx >> 3) & 3, l15 = (idx >> 5) & 15;
    const int ni = (idx >> 9) & 3, ks = (idx >> 11) & 1, g = (idx >> 12) & 3;
    const int k = ks * 32 + oct * 8 + j;
    const int m = ni * 16 + l15;
    W3p[idx] = f2b(w3[g * 4096 + k * 64 + m]);
  } else if (i < N1 + N2 + N3 + N4) {
    const int idx = i - N1 - N2 - N3;
    const int j = idx & 7, oct = (idx >> 3) & 3, l15 = (idx >> 5) & 15;
    const int ni = (idx >> 9) & 1, ks = (idx >> 10) & 1;
    const int oh = (idx >> 11) & 1, ob = (idx >> 12) & 15, g = (idx >> 16) & 3;
    const int k = ks * 32 + oct * 8 + j;
    const int o = ob * 64 + oh * 32 + ni * 16 + l15;
    W4p[idx] = f2b(w4[g * 65536 + k * 1024 + o]);
  }
}

// -------- X de-interleave to TILED bf16: Xt2[g][b>>5][c][b&31][kk] ---------
// tile = 8KB contiguous = one enc1 A-chunk -> pure global_load_lds staging.
__global__ __launch_bounds__(512) void k_prepx(const float* __restrict__ X,
                                               unsigned short* __restrict__ Xt2) {
  const int t = threadIdx.x;
  const int b = blockIdx.x * 2 + (t >> 8);
  const int t256 = t & 255;
  const int k0 = t256 * 4;                 // 4 consecutive k per thread
  const float* p = X + (size_t)b * OBS + t256 * 16;
  const float4_t f0 = *(const float4_t*)(p);
  const float4_t f1 = *(const float4_t*)(p + 4);
  const float4_t f2 = *(const float4_t*)(p + 8);
  const float4_t f3 = *(const float4_t*)(p + 12);
  const int c  = k0 >> 7;
  const int kk = k0 & 127;
  const int b5 = b >> 5, row = b & 31;
#pragma unroll
  for (int g = 0; g < 4; ++g) {
    uint2 v;
    v.x = pack2(f0[g], f1[g]);
    v.y = pack2(f2[g], f3[g]);
    *(uint2*)(Xt2 + ((size_t)((g * 256 + b5) * 8 + c)) * 4096 + row * 128 + kk) = v;
  }
}

// -------- enc1+enc2 fused: Mlg[b][g*128+c] = (h@W2+b2), h=relu(Xg@W1+b1) ---
// grid (256 rb, 4 g) x 256 thr (4 waves; wave = 32-col quarter).
// A dbuf'd via global_load_lds (quad-padded rows); B single-buffered via
// global_load_lds; K-loop touches ONLY LDS. 8 chunks of BK=128.
__global__ __launch_bounds__(256, 3) void k_enc1f(const unsigned short* __restrict__ Xt2,
                                                  const unsigned short* __restrict__ W1p,
                                                  const unsigned short* __restrict__ W2p,
                                                  const float* __restrict__ B1,
                                                  const float* __restrict__ B2,
                                                  float* __restrict__ Mlg) {
  __shared__ __align__(16) char smem[8448 * 2 + 32768];   // A dbuf + B
  char* const BB = smem + 16896;

  const int tid = threadIdx.x;
  const int w   = tid >> 6;
  const int l   = tid & 63;
  const int l15 = l & 15;
  const int oct = l >> 4;
  const int bx  = blockIdx.x;
  const int g   = blockIdx.y;
  const int rb  = bx * 32;
  const int lofs = (l15 * 4 + oct) * 16;   // panel byte offset for this lane

  const char* const xtile = (const char*)Xt2 + (size_t)((g * 256 + bx) * 8) * 8192;
  const char* const w1b   = (const char*)W1p + (size_t)(g * 4 + w) * 65536;

  // prologue: stage chunk 0 (A->buf0, B)
#pragma unroll
  for (int q = 0; q < 2; ++q)
    gl16(xtile + (2 * w + q) * 1024 + l * 16, smem + (2 * w + q) * 1056);
#pragma unroll
  for (int i = 0; i < 8; ++i)
    gl16(w1b + i * 1024 + l * 16, BB + w * 8192 + i * 1024);
  __syncthreads();

  float4_t acc[2][2];
#pragma unroll
  for (int i = 0; i < 2; ++i)
#pragma unroll
    for (int j = 0; j < 2; ++j) acc[i][j] = (float4_t){0.f, 0.f, 0.f, 0.f};

  for (int c = 0; c < 8; ++c) {
    const int cur = c & 1;
    if (c < 7) {   // prefetch next A chunk into alt buffer (overlaps compute)
#pragma unroll
      for (int q = 0; q < 2; ++q)
        gl16(xtile + (c + 1) * 8192 + (2 * w + q) * 1024 + l * 16,
             smem + (cur ^ 1) * 8448 + (2 * w + q) * 1056);
    }
    // compute chunk c: pure LDS
#pragma unroll
    for (int ks = 0; ks < 4; ++ks) {
      short8_t af[2], bf[2];
#pragma unroll
      for (int mi = 0; mi < 2; ++mi)
        af[mi] = *(const short8_t*)(smem + cur * 8448 + AQ(mi * 16 + l15) +
                                    ks * 64 + oct * 16);
#pragma unroll
      for (int ni = 0; ni < 2; ++ni)
        bf[ni] = *(const short8_t*)(BB + w * 8192 + ks * 2048 + ni * 1024 + lofs);
#pragma unroll
      for (int mi = 0; mi < 2; ++mi)
#pragma unroll
        for (int ni = 0; ni < 2; ++ni)
          acc[mi][ni] = __builtin_amdgcn_mfma_f32_16x16x32_bf16(af[mi], bf[ni], acc[mi][ni], 0, 0, 0);
    }
    __syncthreads();                     // done reading B (and A prefetch landed)
    if (c < 7) {                         // stage next B chunk
#pragma unroll
      for (int i = 0; i < 8; ++i)
        gl16(w1b + (c + 1) * 8192 + i * 1024 + l * 16, BB + w * 8192 + i * 1024);
      __syncthreads();
    }
  }

  // h = relu(acc+b1) -> LDS (A region, quad-padded) ; stage W2p -> BB
#pragma unroll
  for (int ni = 0; ni < 2; ++ni) {
    const int col = w * 32 + ni * 16 + l15;
    const float b = B1[g * 128 + col];
#pragma unroll
    for (int mi = 0; mi < 2; ++mi)
#pragma unroll
      for (int j = 0; j < 4; ++j)
        *(unsigned short*)(smem + AQ(mi * 16 + oct * 4 + j) + col * 2) =
            f2b(fmaxf(acc[mi][ni][j] + b, 0.0f));
  }
#pragma unroll
  for (int i = 0; i < 8; ++i)
    gl16((const char*)W2p + g * 32768 + (w * 8 + i) * 1024 + l * 16,
         BB + (w * 8 + i) * 1024);
  __syncthreads();

  // enc2: K=128, pure LDS
  float4_t a2[2][2];
#pragma unroll
  for (int i = 0; i < 2; ++i)
#pragma unroll
    for (int j = 0; j < 2; ++j) a2[i][j] = (float4_t){0.f, 0.f, 0.f, 0.f};
#pragma unroll
  for (int ks = 0; ks < 4; ++ks) {
    short8_t af[2], bf[2];
#pragma unroll
    for (int mi = 0; mi < 2; ++mi)
      af[mi] = *(const short8_t*)(smem + AQ(mi * 16 + l15) + ks * 64 + oct * 16);
#pragma unroll
    for (int ni = 0; ni < 2; ++ni)
      bf[ni] = *(const short8_t*)(BB + (ks * 8 + w * 2 + ni) * 1024 + lofs);
#pragma unroll
    for (int mi = 0; mi < 2; ++mi)
#pragma unroll
      for (int ni = 0; ni < 2; ++ni)
        a2[mi][ni] = __builtin_amdgcn_mfma_f32_16x16x32_bf16(af[mi], bf[ni], a2[mi][ni], 0, 0, 0);
  }
  __syncthreads();   // done reading W2p; mls overlays BB

  float* const mls = (float*)BB;         // [32][132]
#pragma unroll
  for (int ni = 0; ni < 2; ++ni) {
    const int col = w * 32 + ni * 16 + l15;
    const float b = B2[g * 128 + col];
#pragma unroll
    for (int mi = 0; mi < 2; ++mi)
#pragma unroll
      for (int j = 0; j < 4; ++j)
        mls[(mi * 16 + oct * 4 + j) * 132 + col] = a2[mi][ni][j] + b;
  }
  __syncthreads();

  // coalesced copy out: Mlg[b][g*128+c]
  {
    const int row = tid >> 3, c16 = (tid & 7) * 16;
    float* dst = Mlg + (size_t)(rb + row) * 512 + g * 128 + c16;
    const float* src = &mls[row * 132 + c16];
#pragma unroll
    for (int i = 0; i < 4; ++i)
      *(float4*)(dst + i * 4) = *(const float4*)(src + i * 4);
  }
}

// -------- PoE + reparameterize + dec1 -> Hd --------------------------------
// 512 blocks x 256 thr (4 waves; wave = group). Block = 16 batch rows.
__global__ __launch_bounds__(256, 2) void k_samp(const float* __restrict__ Mlg,
                                                 const unsigned short* __restrict__ W3p,
                                                 const float* __restrict__ DB1,
                                                 const float* __restrict__ eps,
                                                 const int*   __restrict__ subset_idx,
                                                 unsigned short* __restrict__ Hd) {
  __shared__ __align__(16) float mls16[16 * 516];        // 33 KB
  __shared__ __align__(16) unsigned short zbs[16 * 72];  // 2.3 KB
  __shared__ __align__(16) char lW3[32768];

  const int tid = threadIdx.x;
  const int w   = tid >> 6;
  const int l   = tid & 63;
  const int l15 = l & 15;
  const int oct = l >> 4;
  const int rb  = blockIdx.x * 16;
  const int lofs = (l15 * 4 + oct) * 16;

  // stage W3p (32KB) async + mls rows
#pragma unroll
  for (int i = 0; i < 8; ++i)
    gl16((const char*)W3p + (w * 8 + i) * 1024 + l * 16, lW3 + (w * 8 + i) * 1024);
  {
    const int row = tid >> 4, c0 = (tid & 15) * 32;
    const float* src = Mlg + (size_t)(rb + row) * 512 + c0;
#pragma unroll
    for (int i = 0; i < 8; ++i)
      *(float4*)&mls16[row * 516 + c0 + i * 4] = *(const float4*)(src + i * 4);
  }
  __syncthreads();

  // PoE + sample
#pragma unroll
  for (int qq = 0; qq < 4; ++qq) {
    const int idx = qq * 256 + tid;
    const int r   = idx >> 6;
    const int ll  = idx & 63;
    const int m   = kMask[subset_idx[rb + r]];
    float tau = 1.0f, num = 0.0f;
#pragma unroll
    for (int gg = 0; gg < 4; ++gg) {
      if (m & (1 << gg)) {
        const float lv = mls16[r * 516 + gg * 128 + 64 + ll];
        const float mu = mls16[r * 516 + gg * 128 + ll];
        const float t  = expf(-lv);
        tau += t;
        num = fmaf(t, mu, num);
      }
    }
    const float zv = num / tau + eps[(size_t)(rb + r) * LATD + ll] * rsqrtf(tau);
    zbs[r * 72 + ll] = f2b(zv);
  }
  __syncthreads();

  // dec1: wave = group w; K=64, pure LDS
  float4_t a3[4];
#pragma unroll
  for (int j = 0; j < 4; ++j) a3[j] = (float4_t){0.f, 0.f, 0.f, 0.f};
#pragma unroll
  for (int ks = 0; ks < 2; ++ks) {
    const short8_t af = *(const short8_t*)((const char*)zbs +
                        (l15 * 72 + ks * 32 + oct * 8) * 2);
#pragma unroll
    for (int ni = 0; ni < 4; ++ni) {
      const short8_t bf = *(const short8_t*)(lW3 + w * 8192 + ks * 4096 +
                                             ni * 1024 + lofs);
      a3[ni] = __builtin_amdgcn_mfma_f32_16x16x32_bf16(af, bf, a3[ni], 0, 0, 0);
    }
  }
#pragma unroll
  for (int ni = 0; ni < 4; ++ni) {
    const int col = w * 64 + ni * 16 + l15;
    const float b = DB1[col];
#pragma unroll
    for (int j = 0; j < 4; ++j)
      Hd[(size_t)(rb + oct * 4 + j) * 256 + col] = f2b(fmaxf(a3[ni][j] + b, 0.0f));
  }
}

// ---------------- dec2: panel-B MFMA + coalesced epilogue (R9, verified) ---
__global__ __launch_bounds__(512) void k_dec2(const unsigned short* __restrict__ Hd,
                                              const unsigned short* __restrict__ W4p,
                                              const float* __restrict__ Bb,
                                              float* __restrict__ Out) {
  __shared__ float obuf[32][264];

  const int tid = threadIdx.x;
  const int w   = tid >> 6;
  const int l   = tid & 63;
  const int g   = w >> 1;
  const int oh  = w & 1;
  const int r0  = blockIdx.x * 32;
  const int ob  = blockIdx.y * 64;
  const int l15 = l & 15;
  const int oct = l >> 4;
  const int lofs = (l15 * 4 + oct) * 8;

  float4_t acc[2][2];
#pragma unroll
  for (int i = 0; i < 2; ++i)
#pragma unroll
    for (int j = 0; j < 2; ++j) acc[i][j] = (float4_t){0.f, 0.f, 0.f, 0.f};

  const unsigned short* bb4 = W4p + ((g * 16 + blockIdx.y) * 2 + oh) * 2048 + lofs;

#pragma unroll
  for (int ks = 0; ks < 2; ++ks) {
    short8_t af[2], bf[2];
#pragma unroll
    for (int mi = 0; mi < 2; ++mi)
      af[mi] = *(const short8_t*)(Hd + (size_t)(r0 + mi * 16 + l15) * 256 +
                                  g * 64 + ks * 32 + oct * 8);
#pragma unroll
    for (int ni = 0; ni < 2; ++ni)
      bf[ni] = *(const short8_t*)(bb4 + ks * 1024 + ni * 512);
#pragma unroll
    for (int mi = 0; mi < 2; ++mi)
#pragma unroll
      for (int ni = 0; ni < 2; ++ni)
        acc[mi][ni] = __builtin_amdgcn_mfma_f32_16x16x32_bf16(af[mi], bf[ni], acc[mi][ni], 0, 0, 0);
  }

#pragma unroll
  for (int ni = 0; ni < 2; ++ni) {
    const int lo = oh * 32 + ni * 16 + l15;
    const float b = Bb[g * 1024 + ob + lo];
#pragma unroll
    for (int mi = 0; mi < 2; ++mi) {
      const int rloc = mi * 16 + oct * 4;
#pragma unroll
      for (int j = 0; j < 4; ++j)
        obuf[rloc + j][4 * lo + g] = acc[mi][ni][j] + b;
    }
  }
  __syncthreads();

#pragma unroll
  for (int i = 0; i < 4; ++i) {
    const int q = tid + i * 512;
    const int row = q >> 6, c4 = q & 63;
    const float4 v = *(const float4*)&obuf[row][c4 * 4];
    *(float4*)(Out + (size_t)(r0 + row) * OBS + 4 * ob + c4 * 4) = v;
  }
}

extern "C" void kernel_launch(void* const* d_in, const int* in_sizes, int n_in,
                              void* d_out, int out_size, void* d_ws, size_t ws_size,
                              hipStream_t stream) {
  const float* X          = (const float*)d_in[0];
  const float* eps        = (const float*)d_in[1];
  const int*   subset_idx = (const int*)  d_in[2];
  const float* enc_w1     = (const float*)d_in[3];
  const float* enc_b1     = (const float*)d_in[4];
  const float* enc_w2     = (const float*)d_in[5];
  const float* enc_b2     = (const float*)d_in[6];
  const float* dec_w1     = (const float*)d_in[7];
  const float* dec_b1     = (const float*)d_in[8];
  const float* dec_w2     = (const float*)d_in[9];
  const float* dec_b2     = (const float*)d_in[10];
  float* out = (float*)d_out;

  char* wsb = (char*)d_ws;
  unsigned short* Xt2 = (unsigned short*)wsb;                                 // 64 MB
  float*          Mlg = (float*)(wsb + (64u << 20));                          // 16 MB
  unsigned short* Hd  = (unsigned short*)(wsb + (80u << 20));                 // 4 MB
  unsigned short* W1p = (unsigned short*)(wsb + (84u << 20));                 // 1 MB
  unsigned short* W2p = (unsigned short*)(wsb + (85u << 20));                 // 128 KB
  unsigned short* W3p = (unsigned short*)(wsb + (85u << 20) + (128u << 10));  // 32 KB
  unsigned short* W4p = (unsigned short*)(wsb + (85u << 20) + (160u << 10));  // 512 KB

  k_prep<<<3392, 256, 0, stream>>>(enc_w1, enc_w2, dec_w1, dec_w2,
                                   W1p, W2p, W3p, W4p);
  k_prepx<<<4096, 512, 0, stream>>>(X, Xt2);
  k_enc1f<<<dim3(256, 4), 256, 0, stream>>>(Xt2, W1p, W2p, enc_b1, enc_b2, Mlg);
  k_samp<<<512, 256, 0, stream>>>(Mlg, W3p, dec_b1, eps, subset_idx, Hd);
  k_dec2<<<dim3(256, 16), 512, 0, stream>>>(Hd, W4p, dec_b2, out);
}